// Round 1
// baseline (181.951 us; speedup 1.0000x reference)
//
#include <hip/hip_runtime.h>
#include <math.h>

#define BB   16
#define CC   4
#define HH   640
#define WW   640
#define HWSZ (HH*WW)        // 409600 pixels per image
#define KM   16             // labels 1..16 tracked; 0 = background (derived)
#define NACC (KM*5)         // 4 channel sums + 1 count per label = 80
#define SIGMA_D 3.0f

// ---------------------------------------------------------------------------
// Kernel 1: per-(image,label) channel sums + counts via register accumulation
// grid = (64, B), block = 256. Each thread register-accumulates 80 values
// (statically indexed -> VGPRs), staggered LDS-atomic block reduce, then one
// global atomicAdd per slot per block into zeroed ws[b*80 + idx].
// ---------------------------------------------------------------------------
__global__ __launch_bounds__(256) void seg_kernel(
    const float* __restrict__ pred, const int* __restrict__ labels,
    float* __restrict__ ws)
{
    const int b = blockIdx.y;
    const int t = threadIdx.x;

    const int4*   lab = (const int4*)(labels + (size_t)b * HWSZ);
    const float4* p0  = (const float4*)(pred + ((size_t)b * CC + 0) * HWSZ);
    const float4* p1  = (const float4*)(pred + ((size_t)b * CC + 1) * HWSZ);
    const float4* p2  = (const float4*)(pred + ((size_t)b * CC + 2) * HWSZ);
    const float4* p3  = (const float4*)(pred + ((size_t)b * CC + 3) * HWSZ);

    const int NGROUPS = HWSZ / 4;          // 102400 float4-groups per image
    const int STRIDE  = gridDim.x * 256;   // 16384

    float acc[NACC];
    #pragma unroll
    for (int i = 0; i < NACC; ++i) acc[i] = 0.f;

    for (int g = blockIdx.x * 256 + t; g < NGROUPS; g += STRIDE) {
        int4   L  = lab[g];
        float4 v0 = p0[g], v1 = p1[g], v2 = p2[g], v3 = p3[g];
        int   lb4[4] = {L.x, L.y, L.z, L.w};
        float a0[4]  = {v0.x, v0.y, v0.z, v0.w};
        float a1[4]  = {v1.x, v1.y, v1.z, v1.w};
        float a2[4]  = {v2.x, v2.y, v2.z, v2.w};
        float a3[4]  = {v3.x, v3.y, v3.z, v3.w};
        #pragma unroll
        for (int j = 0; j < 4; ++j) {
            int lb = lb4[j];
            #pragma unroll
            for (int k = 1; k <= KM; ++k) {
                float m = (lb == k) ? 1.0f : 0.0f;
                acc[(k-1)*5+0] = fmaf(m, a0[j], acc[(k-1)*5+0]);
                acc[(k-1)*5+1] = fmaf(m, a1[j], acc[(k-1)*5+1]);
                acc[(k-1)*5+2] = fmaf(m, a2[j], acc[(k-1)*5+2]);
                acc[(k-1)*5+3] = fmaf(m, a3[j], acc[(k-1)*5+3]);
                acc[(k-1)*5+4] += m;
            }
        }
    }

    // block reduce: staggered LDS atomics (no same-address collisions in a wave)
    __shared__ float sacc[NACC];
    for (int i = t; i < NACC; i += 256) sacc[i] = 0.f;
    __syncthreads();
    int tm = t % NACC;
    #pragma unroll
    for (int s = 0; s < NACC; ++s) {
        int idx = tm + s;
        if (idx >= NACC) idx -= NACC;
        atomicAdd(&sacc[idx], acc[idx]);
    }
    __syncthreads();
    if (t < NACC) atomicAdd(&ws[b * NACC + t], sacc[t]);
}

// ---------------------------------------------------------------------------
// Kernel 2: tiny epilogue — N, f, sum_g, Kb, own/other/scale, scalar out.
// ---------------------------------------------------------------------------
__global__ void finalize_kernel(const float* __restrict__ ws, float* __restrict__ out)
{
    __shared__ float s_sumg[BB], s_P[BB], s_Kb[BB];
    const float F0 = logf(SIGMA_D * SIGMA_D + 1.0f);   // log(10)
    int b = threadIdx.x;
    if (b < BB) {
        const float* w = ws + b * NACC;
        float cnt_sum = 0.f, sum_g = 0.f, Kb = 0.f;
        for (int k = 1; k <= KM; ++k) {
            float s0 = w[(k-1)*5+0], s1 = w[(k-1)*5+1];
            float s2 = w[(k-1)*5+2], s3 = w[(k-1)*5+3];
            float cn = w[(k-1)*5+4];
            float N  = sqrtf(s0*s0 + s1*s1 + s2*s2 + s3*s3);
            float r  = fmaxf(SIGMA_D - N, 0.f);
            float f  = logf(r*r + 1.0f);
            sum_g   += cn * f;
            cnt_sum += cn;
            if (cn > 0.f) Kb = (float)k;
        }
        float c0 = (float)HWSZ - cnt_sum;     // background count
        sum_g += c0 * F0;
        s_sumg[b] = sum_g;
        s_Kb[b]   = Kb;
        s_P[b]    = (Kb > 1.f) ? Kb * (Kb - 1.f) * 0.5f : 0.f;  // P_act
    }
    __syncthreads();
    if (threadIdx.x == 0) {
        double sumP = 0.0;
        for (int i = 0; i < BB; ++i) sumP += (double)s_P[i];
        double total = 0.0;
        for (int i = 0; i < BB; ++i) {
            double Kb   = (double)s_Kb[i];
            double Pact = (double)s_P[i];
            double own  = 0.0;
            if (Kb > 1.0)
                own = (Kb - 1.0) * (double)s_sumg[i]
                    + (double)HWSZ * (Pact - (Kb - 1.0)) * (double)F0;
            double other = (sumP - Pact) * (double)HWSZ * (double)F0;
            double scale = (Kb > 1.0) ? 1.0 / (Kb * (Kb - 1.0)) : Kb;
            total += scale * (own + other);
        }
        out[0] = (float)total;
    }
}

// ---------------------------------------------------------------------------
extern "C" void kernel_launch(void* const* d_in, const int* in_sizes, int n_in,
                              void* d_out, int out_size, void* d_ws, size_t ws_size,
                              hipStream_t stream)
{
    const float* pred   = (const float*)d_in[0];
    const int*   labels = (const int*)d_in[1];
    float*       out    = (float*)d_out;
    float*       ws     = (float*)d_ws;

    hipMemsetAsync(ws, 0, BB * NACC * sizeof(float), stream);

    dim3 grid(64, BB);
    seg_kernel<<<grid, 256, 0, stream>>>(pred, labels, ws);
    finalize_kernel<<<1, 64, 0, stream>>>(ws, out);
}